// Round 2
// baseline (358.797 us; speedup 1.0000x reference)
//
#include <hip/hip_runtime.h>
#include <hip/hip_bf16.h>

// DecorrelatedBatchNorm1d (ZCA whitening), B=65536, F=512, fp32 in/out.
// Pipeline:
//   K1 k_prep:     colsum(x) + xbT = bf16(x)^T (into d_out scratch)
//   K2 k_cov:      S = xbT * xbT^T upper-triangle (bf16 MFMA, split-K, atomics)
//   K3 k_finalize: mean, E = S/(B-1) corrected - I + eps  (fp32 + bf16 copies)
//   K4-6 k_poly64: D = c1E+c2E2+c3E3 + E4*(c4I+c5E+c6E2+c7E3) (Taylor deg 7,
//                  64x64 tiles) + stage2 folds tacc = mean^T D via atomics
//   K7 k_out:      out = (x - mean + x@D - tacc)*weight + bias
//                  (full-width 64x512 blocks; A reg-staged fp32->bf16;
//                   B = Db direct from L2; identity path exact fp32)

#define F 512
#define NBATCH 65536
#define LDT 65536

typedef unsigned short u16;
using bf16x8 = __attribute__((ext_vector_type(8))) short;
using f32x4  = __attribute__((ext_vector_type(4))) float;

// ---- workspace layout (bytes) ----
#define WS_S      0u
#define WS_COLSUM 1048576u
#define WS_TACC   1050624u
#define WS_MEAN   1052672u
#define WS_E      1056768u
#define WS_E2     (WS_E  + 1048576u)
#define WS_E3     (WS_E2 + 1048576u)
#define WS_D      (WS_E3 + 1048576u)   // unused hole (kept for layout stability)
#define WS_EB     (WS_D  + 1048576u)
#define WS_E2B    (WS_EB  + 524288u)
#define WS_QB     (WS_E2B + 524288u)
#define WS_E4B    (WS_QB  + 524288u)
#define WS_DB     (WS_E4B + 524288u)

__device__ __forceinline__ u16 f2bf(float x) {
  union { float f; unsigned u; } v; v.f = x;
  return (u16)((v.u + 0x7fffu + ((v.u >> 16) & 1u)) >> 16);
}

__device__ __forceinline__ void async_cp16(const void* g, void* l) {
  __builtin_amdgcn_global_load_lds(
      (const __attribute__((address_space(1))) unsigned int*)g,
      (__attribute__((address_space(3))) unsigned int*)l, 16, 0, 0);
}

// ---- 128-row tile staging (k_cov) ----
// LDS dest linear; source pre-swizzled: LDS row r chunk c holds global chunk c^(r&7).
__device__ __forceinline__ void stage_tile(u16* dst, const u16* src, size_t stride, int t) {
#pragma unroll
  for (int q = 0; q < 4; ++q) {
    int idx = q * 256 + t;
    int c = idx >> 3, ko = idx & 7;
    async_cp16(src + (size_t)c * stride + (size_t)((ko ^ (c & 7)) << 3), dst + idx * 8);
  }
}

__device__ __forceinline__ void mm_step(const u16* As, const u16* Bs, int wr, int wc,
                                        int l, f32x4 acc[4][4]) {
#pragma unroll
  for (int kh = 0; kh < 2; ++kh) {
    bf16x8 a[4], b[4];
#pragma unroll
    for (int m = 0; m < 4; ++m) {
      int row = wr * 64 + m * 16 + (l & 15);
      int ch = (kh * 4 + (l >> 4)) ^ (row & 7);
      a[m] = *(const bf16x8*)(As + row * 64 + ch * 8);
    }
#pragma unroll
    for (int n = 0; n < 4; ++n) {
      int row = wc * 64 + n * 16 + (l & 15);
      int ch = (kh * 4 + (l >> 4)) ^ (row & 7);
      b[n] = *(const bf16x8*)(Bs + row * 64 + ch * 8);
    }
#pragma unroll
    for (int m = 0; m < 4; ++m)
#pragma unroll
      for (int n = 0; n < 4; ++n)
        acc[m][n] = __builtin_amdgcn_mfma_f32_16x16x32_bf16(a[m], b[n], acc[m][n], 0, 0, 0);
  }
}

// ---- 64-row tile staging (poly) ----
__device__ __forceinline__ void stage64(u16* dst, const u16* src, size_t stride, int t) {
#pragma unroll
  for (int q = 0; q < 2; ++q) {
    int idx = q * 256 + t;
    int r = idx >> 3, ko = idx & 7;
    async_cp16(src + (size_t)r * stride + (size_t)((ko ^ (r & 7)) << 3), dst + idx * 8);
  }
}

__device__ __forceinline__ void mm64(const u16* As, const u16* Bs, int wr, int wc,
                                     int l, f32x4 acc[2][2]) {
#pragma unroll
  for (int kh = 0; kh < 2; ++kh) {
    bf16x8 a[2], b[2];
#pragma unroll
    for (int m = 0; m < 2; ++m) {
      int row = wr * 32 + m * 16 + (l & 15);
      int ch = (kh * 4 + (l >> 4)) ^ (row & 7);
      a[m] = *(const bf16x8*)(As + row * 64 + ch * 8);
    }
#pragma unroll
    for (int n = 0; n < 2; ++n) {
      int row = wc * 32 + n * 16 + (l & 15);
      int ch = (kh * 4 + (l >> 4)) ^ (row & 7);
      b[n] = *(const bf16x8*)(Bs + row * 64 + ch * 8);
    }
#pragma unroll
    for (int m = 0; m < 2; ++m)
#pragma unroll
      for (int n = 0; n < 2; ++n)
        acc[m][n] = __builtin_amdgcn_mfma_f32_16x16x32_bf16(a[m], b[n], acc[m][n], 0, 0, 0);
  }
}

// ---------------- K1: colsum + bf16 transpose ----------------
__global__ __launch_bounds__(256) void k_prep(const float* __restrict__ x,
                                              u16* __restrict__ xbT,
                                              float* __restrict__ colsum) {
  __shared__ __attribute__((aligned(16))) float tile[128 * 65];
  const int t = threadIdx.x;
  const int rt = blockIdx.x, ct = blockIdx.y;
  const int r0 = rt * 128, c0 = ct * 64;
  const int c4 = t & 15, rg = t >> 4;
  float cs0 = 0, cs1 = 0, cs2 = 0, cs3 = 0;
#pragma unroll
  for (int p = 0; p < 8; ++p) {
    int r = rg + p * 16;
    float4 v = *(const float4*)(x + (size_t)(r0 + r) * F + c0 + c4 * 4);
    cs0 += v.x; cs1 += v.y; cs2 += v.z; cs3 += v.w;
    float* tp = tile + r * 65 + c4 * 4;
    tp[0] = v.x; tp[1] = v.y; tp[2] = v.z; tp[3] = v.w;
  }
  __syncthreads();
  const int l = t & 63, w = t >> 6;
  const int a = l & 15, bg = l >> 4;
#pragma unroll
  for (int cp = 0; cp < 4; ++cp) {
    int c = cp * 16 + w * 4 + bg;
#pragma unroll
    for (int h = 0; h < 2; ++h) {
      int rb = 4 * a + 64 * h;
      ushort4 o;
      o.x = f2bf(tile[(rb + 0) * 65 + c]);
      o.y = f2bf(tile[(rb + 1) * 65 + c]);
      o.z = f2bf(tile[(rb + 2) * 65 + c]);
      o.w = f2bf(tile[(rb + 3) * 65 + c]);
      *(ushort4*)(xbT + (size_t)(c0 + c) * LDT + r0 + rb) = o;
    }
  }
  __syncthreads();
  tile[rg * 64 + c4 * 4 + 0] = cs0;
  tile[rg * 64 + c4 * 4 + 1] = cs1;
  tile[rg * 64 + c4 * 4 + 2] = cs2;
  tile[rg * 64 + c4 * 4 + 3] = cs3;
  __syncthreads();
  if (t < 64) {
    float s = 0;
#pragma unroll
    for (int g = 0; g < 16; ++g) s += tile[g * 64 + t];
    atomicAdd(colsum + c0 + t, s);
  }
}

// ---------------- K2: S = X^T X, upper-triangle 128-tiles, split-K ----------------
__global__ __launch_bounds__(256) void k_cov(const u16* __restrict__ xbT,
                                             float* __restrict__ S) {
  __shared__ __attribute__((aligned(16))) u16 As[2][128 * 64];
  __shared__ __attribute__((aligned(16))) u16 Bs[2][128 * 64];
  int tid = blockIdx.x % 10, slab = blockIdx.x / 10;
  int ta, tb;
  if (tid < 4)      { ta = 0; tb = tid; }
  else if (tid < 7) { ta = 1; tb = tid - 3; }
  else if (tid < 9) { ta = 2; tb = tid - 5; }
  else              { ta = 3; tb = 3; }
  const int a0 = ta * 128, b0 = tb * 128;
  const size_t kbase = (size_t)slab * 1024;
  const int t = threadIdx.x;
  const int l = t & 63, w = t >> 6, wr = w >> 1, wc = w & 1;
  f32x4 acc[4][4] = {};
  const u16* Abase = xbT + (size_t)a0 * LDT + kbase;
  const u16* Bbase = xbT + (size_t)b0 * LDT + kbase;
  stage_tile(As[0], Abase, LDT, t);
  stage_tile(Bs[0], Bbase, LDT, t);
  __syncthreads();
  for (int it = 0; it < 16; ++it) {
    int cur = it & 1;
    if (it < 15) {
      stage_tile(As[cur ^ 1], Abase + (it + 1) * 64, LDT, t);
      stage_tile(Bs[cur ^ 1], Bbase + (it + 1) * 64, LDT, t);
    }
    mm_step(As[cur], Bs[cur], wr, wc, l, acc);
    __syncthreads();
  }
#pragma unroll
  for (int m = 0; m < 4; ++m) {
    int rg = a0 + wr * 64 + m * 16 + ((l >> 4) << 2);
#pragma unroll
    for (int n = 0; n < 4; ++n) {
      int cg = b0 + wc * 64 + n * 16 + (l & 15);
#pragma unroll
      for (int r = 0; r < 4; ++r)
        atomicAdd(S + (size_t)(rg + r) * F + cg, acc[m][n][r]);
    }
  }
}

// ---------------- K3: finalize mean + E = cov - I ----------------
__global__ __launch_bounds__(256) void k_finalize(const float* __restrict__ S,
                                                  const float* __restrict__ colsum,
                                                  float* __restrict__ mean,
                                                  float* __restrict__ E,
                                                  u16* __restrict__ Eb) {
  int gid = blockIdx.x * 256 + threadIdx.x;
  int i = gid >> 9, j = gid & 511;
  float mi = colsum[i] * (1.0f / 65536.0f);
  float mj = colsum[j] * (1.0f / 65536.0f);
  float sv = ((i >> 7) <= (j >> 7)) ? S[(size_t)i * F + j] : S[(size_t)j * F + i];
  float cov = (sv - 65536.0f * mi * mj) * (1.0f / 65535.0f);
  float e = cov + ((i == j) ? (0.001f - 1.0f) : 0.0f);
  E[gid] = e;
  Eb[gid] = f2bf(e);
  if (gid < F) mean[gid] = colsum[gid] * (1.0f / 65536.0f);
}

// ---------------- K4-6: polynomial matmuls, 64x64 tiles ----------------
// stg0: E2 = E@E (64 blocks).  stg1: job0 E3 = E2@E + QB; job1 E4B = E2@E2 (128).
// stg2: D = c1E+c2E2+c3E3 + E4@QB -> DB + tacc atomics (64 blocks).
__global__ __launch_bounds__(256) void k_poly64(char* __restrict__ wsb, int stg) {
  __shared__ __attribute__((aligned(16))) u16 As[2][64 * 64];
  __shared__ __attribute__((aligned(16))) u16 Bs[2][64 * 64];
  int bid = blockIdx.x;
  int job = 0, tile = bid;
  if (stg == 1) { job = bid >> 6; tile = bid & 63; }
  const int tr = tile >> 3, tc = tile & 7;
  const int r0 = tr * 64, c0 = tc * 64;
  const u16* Eb  = (const u16*)(wsb + WS_EB);
  const u16* E2b = (const u16*)(wsb + WS_E2B);
  const u16* Ab; const u16* Bb;
  if (stg == 0)      { Ab = Eb;  Bb = Eb; }
  else if (stg == 1) { Ab = E2b; Bb = (job == 0) ? Eb : E2b; }
  else               { Ab = (const u16*)(wsb + WS_E4B); Bb = (const u16*)(wsb + WS_QB); }
  const int t = threadIdx.x;
  const int l = t & 63, w = t >> 6, wr = w >> 1, wc = w & 1;
  f32x4 acc[2][2] = {};
  stage64(As[0], Ab + (size_t)r0 * F, F, t);
  stage64(Bs[0], Bb + (size_t)c0 * F, F, t);
  __syncthreads();
  for (int it = 0; it < 8; ++it) {
    int cur = it & 1;
    if (it < 7) {
      stage64(As[cur ^ 1], Ab + (size_t)r0 * F + (it + 1) * 64, F, t);
      stage64(Bs[cur ^ 1], Bb + (size_t)c0 * F + (it + 1) * 64, F, t);
    }
    mm64(As[cur], Bs[cur], wr, wc, l, acc);
    __syncthreads();
  }
  const float* Ef  = (const float*)(wsb + WS_E);
  const float* E2f = (const float*)(wsb + WS_E2);
  const float* E3f = (const float*)(wsb + WS_E3);
  const float* mean = (const float*)(wsb + WS_MEAN);
  float* tacc = (float*)(wsb + WS_TACC);
  const float c1 = -0.5f, c2 = 0.375f, c3 = -0.3125f;
  const float c4 = 35.0f / 128.0f, c5 = -63.0f / 256.0f;
  const float c6 = 231.0f / 1024.0f, c7 = -429.0f / 2048.0f;
#pragma unroll
  for (int n = 0; n < 2; ++n) {
    int cg = c0 + wc * 32 + n * 16 + (l & 15);
    float ts = 0.0f;
#pragma unroll
    for (int m = 0; m < 2; ++m) {
#pragma unroll
      for (int r = 0; r < 4; ++r) {
        int rg = r0 + wr * 32 + m * 16 + ((l >> 4) << 2) + r;
        size_t o = (size_t)rg * F + cg;
        float v = acc[m][n][r];
        if (stg == 0) {
          ((float*)(wsb + WS_E2))[o] = v;
          ((u16*)(wsb + WS_E2B))[o] = f2bf(v);
        } else if (stg == 1) {
          if (job == 0) {
            ((float*)(wsb + WS_E3))[o] = v;
            float qv = c5 * Ef[o] + c6 * E2f[o] + c7 * v + ((rg == cg) ? c4 : 0.0f);
            ((u16*)(wsb + WS_QB))[o] = f2bf(qv);
          } else {
            ((u16*)(wsb + WS_E4B))[o] = f2bf(v);
          }
        } else {
          float dv = c1 * Ef[o] + c2 * E2f[o] + c3 * E3f[o] + v;
          ((u16*)(wsb + WS_DB))[o] = f2bf(dv);
          ts += mean[rg] * dv;
        }
      }
    }
    if (stg == 2) atomicAdd(tacc + cg, ts);
  }
}

// ---------------- K7: out = (x - mean + x@D - tacc)*w + b ----------------
// Full-width blocks: 64 rows x 512 cols. A: fp32 x reg-staged -> bf16 swizzled LDS.
// B: Db read directly from global (L2-resident, 512 KB).
__global__ __launch_bounds__(256) void k_out(const float* __restrict__ x,
                                             const u16* __restrict__ Db,
                                             const float* __restrict__ mean,
                                             const float* __restrict__ tacc,
                                             const float* __restrict__ wgt,
                                             const float* __restrict__ bias,
                                             float* __restrict__ out) {
  __shared__ __attribute__((aligned(16))) u16 As[2][64 * 64];
  const int i0 = blockIdx.x * 64;
  const int t = threadIdx.x;
  const int l = t & 63, wc = t >> 6;  // wave -> 128-col block
  f32x4 acc[4][8] = {};
  float4 ld[4];
#pragma unroll
  for (int q = 0; q < 4; ++q) {
    int idx = q * 256 + t, r = idx >> 4, kc = idx & 15;
    ld[q] = *(const float4*)(x + (size_t)(i0 + r) * F + kc * 4);
  }
#pragma unroll
  for (int q = 0; q < 4; ++q) {
    int idx = q * 256 + t, r = idx >> 4, kc = idx & 15;
    ushort4 o;
    o.x = f2bf(ld[q].x); o.y = f2bf(ld[q].y); o.z = f2bf(ld[q].z); o.w = f2bf(ld[q].w);
    *(ushort4*)(As[0] + r * 64 + (((kc >> 1) ^ (r & 7)) << 3) + ((kc & 1) << 2)) = o;
  }
  __syncthreads();
  for (int it = 0; it < 8; ++it) {
    int cur = it & 1;
    if (it < 7) {
      int kk = (it + 1) * 64;
#pragma unroll
      for (int q = 0; q < 4; ++q) {
        int idx = q * 256 + t, r = idx >> 4, kc = idx & 15;
        ld[q] = *(const float4*)(x + (size_t)(i0 + r) * F + kk + kc * 4);
      }
    }
#pragma unroll
    for (int kh = 0; kh < 2; ++kh) {
      bf16x8 a[4], b[8];
#pragma unroll
      for (int m = 0; m < 4; ++m) {
        int row = m * 16 + (l & 15);
        int ch = (kh * 4 + (l >> 4)) ^ (row & 7);
        a[m] = *(const bf16x8*)(As[cur] + row * 64 + ch * 8);
      }
#pragma unroll
      for (int n = 0; n < 8; ++n) {
        int j = wc * 128 + n * 16 + (l & 15);
        b[n] = *(const bf16x8*)(Db + (size_t)j * F + it * 64 + kh * 32 + ((l >> 4) << 3));
      }
#pragma unroll
      for (int m = 0; m < 4; ++m)
#pragma unroll
        for (int n = 0; n < 8; ++n)
          acc[m][n] = __builtin_amdgcn_mfma_f32_16x16x32_bf16(a[m], b[n], acc[m][n], 0, 0, 0);
    }
    if (it < 7) {
#pragma unroll
      for (int q = 0; q < 4; ++q) {
        int idx = q * 256 + t, r = idx >> 4, kc = idx & 15;
        ushort4 o;
        o.x = f2bf(ld[q].x); o.y = f2bf(ld[q].y); o.z = f2bf(ld[q].z); o.w = f2bf(ld[q].w);
        *(ushort4*)(As[cur ^ 1] + r * 64 + (((kc >> 1) ^ (r & 7)) << 3) + ((kc & 1) << 2)) = o;
      }
    }
    __syncthreads();
  }
#pragma unroll
  for (int n = 0; n < 8; ++n) {
    int cg = wc * 128 + n * 16 + (l & 15);
    float mv = mean[cg] + tacc[cg];
    float wv = wgt[cg], bv = bias[cg];
#pragma unroll
    for (int m = 0; m < 4; ++m) {
      int rb = i0 + m * 16 + ((l >> 4) << 2);
#pragma unroll
      for (int r = 0; r < 4; ++r) {
        size_t o = (size_t)(rb + r) * F + cg;
        out[o] = (acc[m][n][r] + x[o] - mv) * wv + bv;
      }
    }
  }
}

extern "C" void kernel_launch(void* const* d_in, const int* in_sizes, int n_in,
                              void* d_out, int out_size, void* d_ws, size_t ws_size,
                              hipStream_t stream) {
  (void)in_sizes; (void)n_in; (void)out_size; (void)ws_size;
  const float* x      = (const float*)d_in[0];
  const float* weight = (const float*)d_in[1];
  const float* bias   = (const float*)d_in[2];
  float* out = (float*)d_out;
  char* ws   = (char*)d_ws;
  // xbT (64 MiB) overlays d_out; dead before k_out overwrites d_out.
  u16* xbT = (u16*)d_out;

  float* S      = (float*)(ws + WS_S);
  float* colsum = (float*)(ws + WS_COLSUM);
  float* tacc   = (float*)(ws + WS_TACC);
  float* mean   = (float*)(ws + WS_MEAN);

  hipMemsetAsync(ws, 0, WS_MEAN, stream);  // zero S + colsum + tacc

  k_prep<<<dim3(512, 8), dim3(256), 0, stream>>>(x, xbT, colsum);
  k_cov<<<dim3(640), dim3(256), 0, stream>>>(xbT, S);
  k_finalize<<<dim3(1024), dim3(256), 0, stream>>>(S, colsum, mean,
                                                   (float*)(ws + WS_E),
                                                   (u16*)(ws + WS_EB));
  k_poly64<<<dim3(64), dim3(256), 0, stream>>>(ws, 0);
  k_poly64<<<dim3(128), dim3(256), 0, stream>>>(ws, 1);
  k_poly64<<<dim3(64), dim3(256), 0, stream>>>(ws, 2);
  k_out<<<dim3(1024), dim3(256), 0, stream>>>(x, (u16*)(ws + WS_DB),
                                              mean, tacc, weight, bias, out);
}

// Round 3
// 214.724 us; speedup vs baseline: 1.6710x; 1.6710x over previous
//
#include <hip/hip_runtime.h>
#include <hip/hip_bf16.h>

// DecorrelatedBatchNorm1d (ZCA whitening), B=65536, F=512, fp32 in/out.
// Pipeline:
//   K1 k_prep:     colsum(x) + xbT = bf16(x)^T (into d_out scratch)
//   K2 k_cov:      S = xbT * xbT^T upper-triangle (bf16 MFMA, split-K=32, atomics,
//                  XCD-pinned slab-major)
//   K3 k_finalize: mean, E = S/(B-1) corrected - I + eps  (fp32 + bf16 copies)
//   K4 k_poly s0:  E2 = E@E; G = c3*E + c4*E2          (deg-4 Taylor of (I+E)^-1/2)
//   K5 k_poly s1:  D = c1*E + c2*E2 + E2@G; tacc = mean^T D (atomics)
//   K6 k_out:      out = (x - mean + x@D - tacc)*weight + bias
//                  (128x128 tiles, 8 waves, XCD-pinned so 4 ct of an rt share L2;
//                   identity path exact fp32)

#define F 512
#define LDT 65536

typedef unsigned short u16;
using bf16x8 = __attribute__((ext_vector_type(8))) short;
using f32x4  = __attribute__((ext_vector_type(4))) float;

// ---- workspace layout (bytes) ----
#define WS_S      0u
#define WS_COLSUM 1048576u
#define WS_TACC   1050624u
#define WS_MEAN   1052672u
#define WS_E      1054720u
#define WS_E2     (WS_E   + 1048576u)
#define WS_EB     (WS_E2  + 1048576u)
#define WS_E2B    (WS_EB  + 524288u)
#define WS_GB     (WS_E2B + 524288u)
#define WS_DB     (WS_GB  + 524288u)

__device__ __forceinline__ u16 f2bf(float x) {
  union { float f; unsigned u; } v; v.f = x;
  return (u16)((v.u + 0x7fffu + ((v.u >> 16) & 1u)) >> 16);
}

__device__ __forceinline__ void async_cp16(const void* g, void* l) {
  __builtin_amdgcn_global_load_lds(
      (const __attribute__((address_space(1))) unsigned int*)g,
      (__attribute__((address_space(3))) unsigned int*)l, 16, 0, 0);
}

// ---- [128 rows][64 k] bf16 tile staging, 256-thread variant ----
// LDS dest linear; source pre-swizzled: LDS row r chunk c holds global chunk c^(r&7).
__device__ __forceinline__ void stage_tile(u16* dst, const u16* src, size_t stride, int t) {
#pragma unroll
  for (int q = 0; q < 4; ++q) {
    int idx = q * 256 + t;
    int c = idx >> 3, ko = idx & 7;
    async_cp16(src + (size_t)c * stride + (size_t)((ko ^ (c & 7)) << 3), dst + idx * 8);
  }
}

// ---- same, 512-thread variant ----
__device__ __forceinline__ void stage512(u16* dst, const u16* src, size_t stride, int t) {
#pragma unroll
  for (int q = 0; q < 2; ++q) {
    int idx = q * 512 + t;
    int c = idx >> 3, ko = idx & 7;
    async_cp16(src + (size_t)c * stride + (size_t)((ko ^ (c & 7)) << 3), dst + idx * 8);
  }
}

// ---- [64 rows][64 k] staging (poly) ----
__device__ __forceinline__ void stage64(u16* dst, const u16* src, size_t stride, int t) {
#pragma unroll
  for (int q = 0; q < 2; ++q) {
    int idx = q * 256 + t;
    int r = idx >> 3, ko = idx & 7;
    async_cp16(src + (size_t)r * stride + (size_t)((ko ^ (r & 7)) << 3), dst + idx * 8);
  }
}

// 128x128 tile step, 4 waves (k_cov): 16 MFMA/kh-pair per wave
__device__ __forceinline__ void mm_step(const u16* As, const u16* Bs, int wr, int wc,
                                        int l, f32x4 acc[4][4]) {
#pragma unroll
  for (int kh = 0; kh < 2; ++kh) {
    bf16x8 a[4], b[4];
#pragma unroll
    for (int m = 0; m < 4; ++m) {
      int row = wr * 64 + m * 16 + (l & 15);
      int ch = (kh * 4 + (l >> 4)) ^ (row & 7);
      a[m] = *(const bf16x8*)(As + row * 64 + ch * 8);
    }
#pragma unroll
    for (int n = 0; n < 4; ++n) {
      int row = wc * 64 + n * 16 + (l & 15);
      int ch = (kh * 4 + (l >> 4)) ^ (row & 7);
      b[n] = *(const bf16x8*)(Bs + row * 64 + ch * 8);
    }
#pragma unroll
    for (int m = 0; m < 4; ++m)
#pragma unroll
      for (int n = 0; n < 4; ++n)
        acc[m][n] = __builtin_amdgcn_mfma_f32_16x16x32_bf16(a[m], b[n], acc[m][n], 0, 0, 0);
  }
}

// 128x128 tile step, 8 waves (k_out): wave-tile 64x32, 8 MFMA/kh
__device__ __forceinline__ void mm_step8(const u16* As, const u16* Bs, int wr, int wc,
                                         int l, f32x4 acc[4][2]) {
#pragma unroll
  for (int kh = 0; kh < 2; ++kh) {
    bf16x8 a[4], b[2];
#pragma unroll
    for (int m = 0; m < 4; ++m) {
      int row = wr * 64 + m * 16 + (l & 15);
      int ch = (kh * 4 + (l >> 4)) ^ (row & 7);
      a[m] = *(const bf16x8*)(As + row * 64 + ch * 8);
    }
#pragma unroll
    for (int n = 0; n < 2; ++n) {
      int row = wc * 32 + n * 16 + (l & 15);
      int ch = (kh * 4 + (l >> 4)) ^ (row & 7);
      b[n] = *(const bf16x8*)(Bs + row * 64 + ch * 8);
    }
#pragma unroll
    for (int m = 0; m < 4; ++m)
#pragma unroll
      for (int n = 0; n < 2; ++n)
        acc[m][n] = __builtin_amdgcn_mfma_f32_16x16x32_bf16(a[m], b[n], acc[m][n], 0, 0, 0);
  }
}

// 64x64 tile step, 4 waves (poly): wave-tile 32x32
__device__ __forceinline__ void mm64(const u16* As, const u16* Bs, int wr, int wc,
                                     int l, f32x4 acc[2][2]) {
#pragma unroll
  for (int kh = 0; kh < 2; ++kh) {
    bf16x8 a[2], b[2];
#pragma unroll
    for (int m = 0; m < 2; ++m) {
      int row = wr * 32 + m * 16 + (l & 15);
      int ch = (kh * 4 + (l >> 4)) ^ (row & 7);
      a[m] = *(const bf16x8*)(As + row * 64 + ch * 8);
    }
#pragma unroll
    for (int n = 0; n < 2; ++n) {
      int row = wc * 32 + n * 16 + (l & 15);
      int ch = (kh * 4 + (l >> 4)) ^ (row & 7);
      b[n] = *(const bf16x8*)(Bs + row * 64 + ch * 8);
    }
#pragma unroll
    for (int m = 0; m < 2; ++m)
#pragma unroll
      for (int n = 0; n < 2; ++n)
        acc[m][n] = __builtin_amdgcn_mfma_f32_16x16x32_bf16(a[m], b[n], acc[m][n], 0, 0, 0);
  }
}

// ---------------- K1: colsum + bf16 transpose ----------------
__global__ __launch_bounds__(256) void k_prep(const float* __restrict__ x,
                                              u16* __restrict__ xbT,
                                              float* __restrict__ colsum) {
  __shared__ __attribute__((aligned(16))) float tile[128 * 65];
  const int t = threadIdx.x;
  const int rt = blockIdx.x, ct = blockIdx.y;
  const int r0 = rt * 128, c0 = ct * 64;
  const int c4 = t & 15, rg = t >> 4;
  float cs0 = 0, cs1 = 0, cs2 = 0, cs3 = 0;
#pragma unroll
  for (int p = 0; p < 8; ++p) {
    int r = rg + p * 16;
    float4 v = *(const float4*)(x + (size_t)(r0 + r) * F + c0 + c4 * 4);
    cs0 += v.x; cs1 += v.y; cs2 += v.z; cs3 += v.w;
    float* tp = tile + r * 65 + c4 * 4;
    tp[0] = v.x; tp[1] = v.y; tp[2] = v.z; tp[3] = v.w;
  }
  __syncthreads();
  const int l = t & 63, w = t >> 6;
  const int a = l & 15, bg = l >> 4;
#pragma unroll
  for (int cp = 0; cp < 4; ++cp) {
    int c = cp * 16 + w * 4 + bg;
#pragma unroll
    for (int h = 0; h < 2; ++h) {
      int rb = 4 * a + 64 * h;
      ushort4 o;
      o.x = f2bf(tile[(rb + 0) * 65 + c]);
      o.y = f2bf(tile[(rb + 1) * 65 + c]);
      o.z = f2bf(tile[(rb + 2) * 65 + c]);
      o.w = f2bf(tile[(rb + 3) * 65 + c]);
      *(ushort4*)(xbT + (size_t)(c0 + c) * LDT + r0 + rb) = o;
    }
  }
  __syncthreads();
  tile[rg * 64 + c4 * 4 + 0] = cs0;
  tile[rg * 64 + c4 * 4 + 1] = cs1;
  tile[rg * 64 + c4 * 4 + 2] = cs2;
  tile[rg * 64 + c4 * 4 + 3] = cs3;
  __syncthreads();
  if (t < 64) {
    float s = 0;
#pragma unroll
    for (int g = 0; g < 16; ++g) s += tile[g * 64 + t];
    atomicAdd(colsum + c0 + t, s);
  }
}

// ---------------- K2: S = X^T X, upper-triangle 128-tiles, split-K=32 ----------------
// 320 blocks, XCD-pinned: xcd b&7 handles slabs xcd*4..xcd*4+3 (panels L2-resident).
__global__ __launch_bounds__(256) void k_cov(const u16* __restrict__ xbT,
                                             float* __restrict__ S) {
  __shared__ __attribute__((aligned(16))) u16 As[2][128 * 64];
  __shared__ __attribute__((aligned(16))) u16 Bs[2][128 * 64];
  const int b = blockIdx.x;
  const int i = b >> 3;               // 0..39
  const int slab = (b & 7) * 4 + i / 10;
  const int tid = i % 10;
  int ta, tb;
  if (tid < 4)      { ta = 0; tb = tid; }
  else if (tid < 7) { ta = 1; tb = tid - 3; }
  else if (tid < 9) { ta = 2; tb = tid - 5; }
  else              { ta = 3; tb = 3; }
  const int a0 = ta * 128, b0 = tb * 128;
  const size_t kbase = (size_t)slab * 2048;
  const int t = threadIdx.x;
  const int l = t & 63, w = t >> 6, wr = w >> 1, wc = w & 1;
  f32x4 acc[4][4] = {};
  const u16* Abase = xbT + (size_t)a0 * LDT + kbase;
  const u16* Bbase = xbT + (size_t)b0 * LDT + kbase;
  stage_tile(As[0], Abase, LDT, t);
  stage_tile(Bs[0], Bbase, LDT, t);
  __syncthreads();
  for (int it = 0; it < 32; ++it) {
    int cur = it & 1;
    if (it < 31) {
      stage_tile(As[cur ^ 1], Abase + (it + 1) * 64, LDT, t);
      stage_tile(Bs[cur ^ 1], Bbase + (it + 1) * 64, LDT, t);
    }
    mm_step(As[cur], Bs[cur], wr, wc, l, acc);
    __syncthreads();
  }
#pragma unroll
  for (int m = 0; m < 4; ++m) {
    int rg = a0 + wr * 64 + m * 16 + ((l >> 4) << 2);
#pragma unroll
    for (int n = 0; n < 4; ++n) {
      int cg = b0 + wc * 64 + n * 16 + (l & 15);
#pragma unroll
      for (int r = 0; r < 4; ++r)
        atomicAdd(S + (size_t)(rg + r) * F + cg, acc[m][n][r]);
    }
  }
}

// ---------------- K3: finalize mean + E = cov - I ----------------
__global__ __launch_bounds__(256) void k_finalize(const float* __restrict__ S,
                                                  const float* __restrict__ colsum,
                                                  float* __restrict__ mean,
                                                  float* __restrict__ E,
                                                  u16* __restrict__ Eb) {
  int gid = blockIdx.x * 256 + threadIdx.x;
  int i = gid >> 9, j = gid & 511;
  float mi = colsum[i] * (1.0f / 65536.0f);
  float mj = colsum[j] * (1.0f / 65536.0f);
  float sv = ((i >> 7) <= (j >> 7)) ? S[(size_t)i * F + j] : S[(size_t)j * F + i];
  float cov = (sv - 65536.0f * mi * mj) * (1.0f / 65535.0f);
  float e = cov + ((i == j) ? (0.001f - 1.0f) : 0.0f);
  E[gid] = e;
  Eb[gid] = f2bf(e);
  if (gid < F) mean[gid] = colsum[gid] * (1.0f / 65536.0f);
}

// ---------------- K4/K5: degree-4 Taylor of (I+E)^(-1/2) ----------------
// stg0: E2 = E@E; also G = c3*E + c4*E2 (bf16).  64 blocks.
// stg1: D = c1*E + c2*E2 + E2@G -> DB (bf16); tacc += mean^T D (atomics). 64 blocks.
__global__ __launch_bounds__(256) void k_poly(char* __restrict__ wsb, int stg) {
  __shared__ __attribute__((aligned(16))) u16 As[2][64 * 64];
  __shared__ __attribute__((aligned(16))) u16 Bs[2][64 * 64];
  const int tile = blockIdx.x;
  const int tr = tile >> 3, tc = tile & 7;
  const int r0 = tr * 64, c0 = tc * 64;
  const u16* Eb  = (const u16*)(wsb + WS_EB);
  const u16* E2b = (const u16*)(wsb + WS_E2B);
  const u16* Gb  = (const u16*)(wsb + WS_GB);
  const u16* Ab; const u16* Bb;
  if (stg == 0) { Ab = Eb;  Bb = Eb; }
  else          { Ab = E2b; Bb = Gb; }
  const int t = threadIdx.x;
  const int l = t & 63, w = t >> 6, wr = w >> 1, wc = w & 1;
  f32x4 acc[2][2] = {};
  stage64(As[0], Ab + (size_t)r0 * F, F, t);
  stage64(Bs[0], Bb + (size_t)c0 * F, F, t);
  __syncthreads();
  for (int it = 0; it < 8; ++it) {
    int cur = it & 1;
    if (it < 7) {
      stage64(As[cur ^ 1], Ab + (size_t)r0 * F + (it + 1) * 64, F, t);
      stage64(Bs[cur ^ 1], Bb + (size_t)c0 * F + (it + 1) * 64, F, t);
    }
    mm64(As[cur], Bs[cur], wr, wc, l, acc);
    __syncthreads();
  }
  const float* Ef  = (const float*)(wsb + WS_E);
  const float* E2f = (const float*)(wsb + WS_E2);
  const float* mean = (const float*)(wsb + WS_MEAN);
  float* tacc = (float*)(wsb + WS_TACC);
  const float c1 = -0.5f, c2 = 0.375f, c3 = -0.3125f, c4 = 35.0f / 128.0f;
#pragma unroll
  for (int n = 0; n < 2; ++n) {
    int cg = c0 + wc * 32 + n * 16 + (l & 15);
    float ts = 0.0f;
#pragma unroll
    for (int m = 0; m < 2; ++m) {
#pragma unroll
      for (int r = 0; r < 4; ++r) {
        int rg = r0 + wr * 32 + m * 16 + ((l >> 4) << 2) + r;
        size_t o = (size_t)rg * F + cg;
        float v = acc[m][n][r];
        if (stg == 0) {
          ((float*)(wsb + WS_E2))[o] = v;
          ((u16*)(wsb + WS_E2B))[o] = f2bf(v);
          ((u16*)(wsb + WS_GB))[o]  = f2bf(c3 * Ef[o] + c4 * v);
        } else {
          float dv = c1 * Ef[o] + c2 * E2f[o] + v;
          ((u16*)(wsb + WS_DB))[o] = f2bf(dv);
          ts += mean[rg] * dv;
        }
      }
    }
    if (stg == 1) atomicAdd(tacc + cg, ts);
  }
}

// ---------------- K6: out = (x - mean + x@D - tacc)*w + b ----------------
// 128x128 tiles, 8 waves (wave-tile 64x32). XCD-pinned: the 4 column-tiles of a
// row-panel run consecutively on ONE XCD -> x fetched once into that L2.
__global__ __launch_bounds__(512) void k_out(const float* __restrict__ x,
                                             const u16* __restrict__ Db,
                                             const float* __restrict__ mean,
                                             const float* __restrict__ tacc,
                                             const float* __restrict__ wgt,
                                             const float* __restrict__ bias,
                                             float* __restrict__ out) {
  __shared__ __attribute__((aligned(16))) u16 As[2][128 * 64];
  __shared__ __attribute__((aligned(16))) u16 Bs[2][128 * 64];
  const int b = blockIdx.x;
  const int i = b >> 3;
  const int rt = (b & 7) * 64 + (i >> 2), ct = i & 3;
  const int i0 = rt * 128, j0 = ct * 128;
  const int t = threadIdx.x;
  const int l = t & 63, w = t >> 6, wr = w >> 2, wc = w & 3;
  f32x4 acc[4][2] = {};
  float4 ld[4];
  stage512(Bs[0], Db + (size_t)j0 * F, F, t);
#pragma unroll
  for (int q = 0; q < 4; ++q) {
    int idx = q * 512 + t, r = idx >> 4, kc = idx & 15;
    ld[q] = *(const float4*)(x + (size_t)(i0 + r) * F + kc * 4);
  }
#pragma unroll
  for (int q = 0; q < 4; ++q) {
    int idx = q * 512 + t, r = idx >> 4, kc = idx & 15;
    ushort4 o;
    o.x = f2bf(ld[q].x); o.y = f2bf(ld[q].y); o.z = f2bf(ld[q].z); o.w = f2bf(ld[q].w);
    *(ushort4*)(As[0] + r * 64 + (((kc >> 1) ^ (r & 7)) << 3) + ((kc & 1) << 2)) = o;
  }
  __syncthreads();
  for (int it = 0; it < 8; ++it) {
    int cur = it & 1;
    if (it < 7) {
      int kk = (it + 1) * 64;
#pragma unroll
      for (int q = 0; q < 4; ++q) {
        int idx = q * 512 + t, r = idx >> 4, kc = idx & 15;
        ld[q] = *(const float4*)(x + (size_t)(i0 + r) * F + kk + kc * 4);
      }
      stage512(Bs[cur ^ 1], Db + (size_t)j0 * F + kk, F, t);
    }
    mm_step8(As[cur], Bs[cur], wr, wc, l, acc);
    if (it < 7) {
#pragma unroll
      for (int q = 0; q < 4; ++q) {
        int idx = q * 512 + t, r = idx >> 4, kc = idx & 15;
        ushort4 o;
        o.x = f2bf(ld[q].x); o.y = f2bf(ld[q].y); o.z = f2bf(ld[q].z); o.w = f2bf(ld[q].w);
        *(ushort4*)(As[cur ^ 1] + r * 64 + (((kc >> 1) ^ (r & 7)) << 3) + ((kc & 1) << 2)) = o;
      }
    }
    __syncthreads();
  }
#pragma unroll
  for (int n = 0; n < 2; ++n) {
    int cg = j0 + wc * 32 + n * 16 + (l & 15);
    float mv = mean[cg] + tacc[cg];
    float wv = wgt[cg], bv = bias[cg];
#pragma unroll
    for (int m = 0; m < 4; ++m) {
      int rb = i0 + wr * 64 + m * 16 + ((l >> 4) << 2);
#pragma unroll
      for (int r = 0; r < 4; ++r) {
        size_t o = (size_t)(rb + r) * F + cg;
        out[o] = (acc[m][n][r] + x[o] - mv) * wv + bv;
      }
    }
  }
}

extern "C" void kernel_launch(void* const* d_in, const int* in_sizes, int n_in,
                              void* d_out, int out_size, void* d_ws, size_t ws_size,
                              hipStream_t stream) {
  (void)in_sizes; (void)n_in; (void)out_size; (void)ws_size;
  const float* x      = (const float*)d_in[0];
  const float* weight = (const float*)d_in[1];
  const float* bias   = (const float*)d_in[2];
  float* out = (float*)d_out;
  char* ws   = (char*)d_ws;
  // xbT (64 MiB) overlays d_out; dead before k_out overwrites d_out.
  u16* xbT = (u16*)d_out;

  float* S      = (float*)(ws + WS_S);
  float* colsum = (float*)(ws + WS_COLSUM);
  float* tacc   = (float*)(ws + WS_TACC);
  float* mean   = (float*)(ws + WS_MEAN);

  hipMemsetAsync(ws, 0, WS_MEAN, stream);  // zero S + colsum + tacc

  k_prep<<<dim3(512, 8), dim3(256), 0, stream>>>(x, xbT, colsum);
  k_cov<<<dim3(320), dim3(256), 0, stream>>>(xbT, S);
  k_finalize<<<dim3(1024), dim3(256), 0, stream>>>(S, colsum, mean,
                                                   (float*)(ws + WS_E),
                                                   (u16*)(ws + WS_EB));
  k_poly<<<dim3(64), dim3(256), 0, stream>>>(ws, 0);
  k_poly<<<dim3(64), dim3(256), 0, stream>>>(ws, 1);
  k_out<<<dim3(2048), dim3(512), 0, stream>>>(x, (u16*)(ws + WS_DB),
                                              mean, tacc, weight, bias, out);
}

// Round 4
// 210.454 us; speedup vs baseline: 1.7049x; 1.0203x over previous
//
#include <hip/hip_runtime.h>
#include <hip/hip_bf16.h>

// DecorrelatedBatchNorm1d (ZCA whitening), B=65536, F=512, fp32 in/out.
// Pipeline:
//   K1 k_prep:     colsum(x) + xbT = bf16(x)^T (d_out scratch) [+ xb row-major in ws]
//   K2 k_cov:      S = xbT * xbT^T upper-triangle (bf16 MFMA, split-K=32, atomics)
//   K3 k_finalize: mean, E = S/(B-1) corrected - I + eps
//   K4 k_poly s0:  E2 = E@E; G = c3*E + c4*E2      (deg-4 Taylor of (I+E)^-1/2)
//   K5 k_poly s1:  W = I + c1*E + c2*E2 + E2@G -> Wb; tacc = mean^T W (atomics)
//   K6 k_out:      out = (x@W - tacc)*weight + bias     (full bf16 MFMA path)
//                  big-ws: A = xb via global_load_lds (no staging VALU)
//                  small-ws fallback: A = fp32 x reg-staged -> bf16 LDS

#define F 512
#define LDT 65536

typedef unsigned short u16;
using bf16x8 = __attribute__((ext_vector_type(8))) short;
using f32x4  = __attribute__((ext_vector_type(4))) float;

// ---- workspace layout (bytes) ----
#define WS_S      0u
#define WS_COLSUM 1048576u
#define WS_TACC   1050624u
#define WS_MEAN   1052672u
#define WS_E      1054720u
#define WS_E2     (WS_E   + 1048576u)
#define WS_EB     (WS_E2  + 1048576u)
#define WS_E2B    (WS_EB  + 524288u)
#define WS_GB     (WS_E2B + 524288u)
#define WS_WB     (WS_GB  + 524288u)
#define WS_XB     (WS_WB  + 524288u)
#define WS_NEED_BIG (WS_XB + 67108864u)

__device__ __forceinline__ u16 f2bf(float x) {
  union { float f; unsigned u; } v; v.f = x;
  return (u16)((v.u + 0x7fffu + ((v.u >> 16) & 1u)) >> 16);
}

__device__ __forceinline__ void async_cp16(const void* g, void* l) {
  __builtin_amdgcn_global_load_lds(
      (const __attribute__((address_space(1))) unsigned int*)g,
      (__attribute__((address_space(3))) unsigned int*)l, 16, 0, 0);
}

// ---- [128 rows][64 k] bf16 tile staging ----
// LDS dest linear; source pre-swizzled: LDS row r chunk c holds global chunk c^(r&7).
__device__ __forceinline__ void stage_tile(u16* dst, const u16* src, size_t stride, int t) {
#pragma unroll
  for (int q = 0; q < 4; ++q) {
    int idx = q * 256 + t;
    int c = idx >> 3, ko = idx & 7;
    async_cp16(src + (size_t)c * stride + (size_t)((ko ^ (c & 7)) << 3), dst + idx * 8);
  }
}

__device__ __forceinline__ void stage512(u16* dst, const u16* src, size_t stride, int t) {
#pragma unroll
  for (int q = 0; q < 2; ++q) {
    int idx = q * 512 + t;
    int c = idx >> 3, ko = idx & 7;
    async_cp16(src + (size_t)c * stride + (size_t)((ko ^ (c & 7)) << 3), dst + idx * 8);
  }
}

__device__ __forceinline__ void stage64(u16* dst, const u16* src, size_t stride, int t) {
#pragma unroll
  for (int q = 0; q < 2; ++q) {
    int idx = q * 256 + t;
    int r = idx >> 3, ko = idx & 7;
    async_cp16(src + (size_t)r * stride + (size_t)((ko ^ (r & 7)) << 3), dst + idx * 8);
  }
}

// 128x128 tile step, 4 waves (k_cov)
__device__ __forceinline__ void mm_step(const u16* As, const u16* Bs, int wr, int wc,
                                        int l, f32x4 acc[4][4]) {
#pragma unroll
  for (int kh = 0; kh < 2; ++kh) {
    bf16x8 a[4], b[4];
#pragma unroll
    for (int m = 0; m < 4; ++m) {
      int row = wr * 64 + m * 16 + (l & 15);
      int ch = (kh * 4 + (l >> 4)) ^ (row & 7);
      a[m] = *(const bf16x8*)(As + row * 64 + ch * 8);
    }
#pragma unroll
    for (int n = 0; n < 4; ++n) {
      int row = wc * 64 + n * 16 + (l & 15);
      int ch = (kh * 4 + (l >> 4)) ^ (row & 7);
      b[n] = *(const bf16x8*)(Bs + row * 64 + ch * 8);
    }
#pragma unroll
    for (int m = 0; m < 4; ++m)
#pragma unroll
      for (int n = 0; n < 4; ++n)
        acc[m][n] = __builtin_amdgcn_mfma_f32_16x16x32_bf16(a[m], b[n], acc[m][n], 0, 0, 0);
  }
}

// 128x128 tile step, 8 waves (k_out): wave-tile 64x32
__device__ __forceinline__ void mm_step8(const u16* As, const u16* Bs, int wr, int wc,
                                         int l, f32x4 acc[4][2]) {
#pragma unroll
  for (int kh = 0; kh < 2; ++kh) {
    bf16x8 a[4], b[2];
#pragma unroll
    for (int m = 0; m < 4; ++m) {
      int row = wr * 64 + m * 16 + (l & 15);
      int ch = (kh * 4 + (l >> 4)) ^ (row & 7);
      a[m] = *(const bf16x8*)(As + row * 64 + ch * 8);
    }
#pragma unroll
    for (int n = 0; n < 2; ++n) {
      int row = wc * 32 + n * 16 + (l & 15);
      int ch = (kh * 4 + (l >> 4)) ^ (row & 7);
      b[n] = *(const bf16x8*)(Bs + row * 64 + ch * 8);
    }
#pragma unroll
    for (int m = 0; m < 4; ++m)
#pragma unroll
      for (int n = 0; n < 2; ++n)
        acc[m][n] = __builtin_amdgcn_mfma_f32_16x16x32_bf16(a[m], b[n], acc[m][n], 0, 0, 0);
  }
}

// 64x64 tile step, 4 waves (poly)
__device__ __forceinline__ void mm64(const u16* As, const u16* Bs, int wr, int wc,
                                     int l, f32x4 acc[2][2]) {
#pragma unroll
  for (int kh = 0; kh < 2; ++kh) {
    bf16x8 a[2], b[2];
#pragma unroll
    for (int m = 0; m < 2; ++m) {
      int row = wr * 32 + m * 16 + (l & 15);
      int ch = (kh * 4 + (l >> 4)) ^ (row & 7);
      a[m] = *(const bf16x8*)(As + row * 64 + ch * 8);
    }
#pragma unroll
    for (int n = 0; n < 2; ++n) {
      int row = wc * 32 + n * 16 + (l & 15);
      int ch = (kh * 4 + (l >> 4)) ^ (row & 7);
      b[n] = *(const bf16x8*)(Bs + row * 64 + ch * 8);
    }
#pragma unroll
    for (int m = 0; m < 2; ++m)
#pragma unroll
      for (int n = 0; n < 2; ++n)
        acc[m][n] = __builtin_amdgcn_mfma_f32_16x16x32_bf16(a[m], b[n], acc[m][n], 0, 0, 0);
  }
}

// ---------------- K1: colsum + bf16 transpose [+ row-major bf16 copy] ----------------
__global__ __launch_bounds__(256) void k_prep(const float* __restrict__ x,
                                              u16* __restrict__ xbT,
                                              float* __restrict__ colsum,
                                              u16* __restrict__ xb) {
  __shared__ __attribute__((aligned(16))) float tile[128 * 65];
  const int t = threadIdx.x;
  const int rt = blockIdx.x, ct = blockIdx.y;
  const int r0 = rt * 128, c0 = ct * 64;
  const int c4 = t & 15, rg = t >> 4;
  float cs0 = 0, cs1 = 0, cs2 = 0, cs3 = 0;
#pragma unroll
  for (int p = 0; p < 8; ++p) {
    int r = rg + p * 16;
    float4 v = *(const float4*)(x + (size_t)(r0 + r) * F + c0 + c4 * 4);
    cs0 += v.x; cs1 += v.y; cs2 += v.z; cs3 += v.w;
    float* tp = tile + r * 65 + c4 * 4;
    tp[0] = v.x; tp[1] = v.y; tp[2] = v.z; tp[3] = v.w;
    if (xb) {
      ushort4 o;
      o.x = f2bf(v.x); o.y = f2bf(v.y); o.z = f2bf(v.z); o.w = f2bf(v.w);
      *(ushort4*)(xb + (size_t)(r0 + r) * F + c0 + c4 * 4) = o;
    }
  }
  __syncthreads();
  const int l = t & 63, w = t >> 6;
  const int a = l & 15, bg = l >> 4;
#pragma unroll
  for (int cp = 0; cp < 4; ++cp) {
    int c = cp * 16 + w * 4 + bg;
#pragma unroll
    for (int h = 0; h < 2; ++h) {
      int rb = 4 * a + 64 * h;
      ushort4 o;
      o.x = f2bf(tile[(rb + 0) * 65 + c]);
      o.y = f2bf(tile[(rb + 1) * 65 + c]);
      o.z = f2bf(tile[(rb + 2) * 65 + c]);
      o.w = f2bf(tile[(rb + 3) * 65 + c]);
      *(ushort4*)(xbT + (size_t)(c0 + c) * LDT + r0 + rb) = o;
    }
  }
  __syncthreads();
  tile[rg * 64 + c4 * 4 + 0] = cs0;
  tile[rg * 64 + c4 * 4 + 1] = cs1;
  tile[rg * 64 + c4 * 4 + 2] = cs2;
  tile[rg * 64 + c4 * 4 + 3] = cs3;
  __syncthreads();
  if (t < 64) {
    float s = 0;
#pragma unroll
    for (int g = 0; g < 16; ++g) s += tile[g * 64 + t];
    atomicAdd(colsum + c0 + t, s);
  }
}

// ---------------- K2: S = X^T X, upper-triangle 128-tiles, split-K=32 ----------------
__global__ __launch_bounds__(256) void k_cov(const u16* __restrict__ xbT,
                                             float* __restrict__ S) {
  __shared__ __attribute__((aligned(16))) u16 As[2][128 * 64];
  __shared__ __attribute__((aligned(16))) u16 Bs[2][128 * 64];
  const int b = blockIdx.x;
  const int i = b >> 3;               // 0..39
  const int slab = (b & 7) * 4 + i / 10;
  const int tid = i % 10;
  int ta, tb;
  if (tid < 4)      { ta = 0; tb = tid; }
  else if (tid < 7) { ta = 1; tb = tid - 3; }
  else if (tid < 9) { ta = 2; tb = tid - 5; }
  else              { ta = 3; tb = 3; }
  const int a0 = ta * 128, b0 = tb * 128;
  const size_t kbase = (size_t)slab * 2048;
  const int t = threadIdx.x;
  const int l = t & 63, w = t >> 6, wr = w >> 1, wc = w & 1;
  f32x4 acc[4][4] = {};
  const u16* Abase = xbT + (size_t)a0 * LDT + kbase;
  const u16* Bbase = xbT + (size_t)b0 * LDT + kbase;
  stage_tile(As[0], Abase, LDT, t);
  stage_tile(Bs[0], Bbase, LDT, t);
  __syncthreads();
  for (int it = 0; it < 32; ++it) {
    int cur = it & 1;
    if (it < 31) {
      stage_tile(As[cur ^ 1], Abase + (it + 1) * 64, LDT, t);
      stage_tile(Bs[cur ^ 1], Bbase + (it + 1) * 64, LDT, t);
    }
    mm_step(As[cur], Bs[cur], wr, wc, l, acc);
    __syncthreads();
  }
#pragma unroll
  for (int m = 0; m < 4; ++m) {
    int rg = a0 + wr * 64 + m * 16 + ((l >> 4) << 2);
#pragma unroll
    for (int n = 0; n < 4; ++n) {
      int cg = b0 + wc * 64 + n * 16 + (l & 15);
#pragma unroll
      for (int r = 0; r < 4; ++r)
        atomicAdd(S + (size_t)(rg + r) * F + cg, acc[m][n][r]);
    }
  }
}

// ---------------- K3: finalize mean + E = cov - I ----------------
__global__ __launch_bounds__(256) void k_finalize(const float* __restrict__ S,
                                                  const float* __restrict__ colsum,
                                                  float* __restrict__ mean,
                                                  float* __restrict__ E,
                                                  u16* __restrict__ Eb) {
  int gid = blockIdx.x * 256 + threadIdx.x;
  int i = gid >> 9, j = gid & 511;
  float mi = colsum[i] * (1.0f / 65536.0f);
  float mj = colsum[j] * (1.0f / 65536.0f);
  float sv = ((i >> 7) <= (j >> 7)) ? S[(size_t)i * F + j] : S[(size_t)j * F + i];
  float cov = (sv - 65536.0f * mi * mj) * (1.0f / 65535.0f);
  float e = cov + ((i == j) ? (0.001f - 1.0f) : 0.0f);
  E[gid] = e;
  Eb[gid] = f2bf(e);
  if (gid < F) mean[gid] = colsum[gid] * (1.0f / 65536.0f);
}

// ---------------- K4/K5: degree-4 Taylor of (I+E)^(-1/2) ----------------
// stg0: E2 = E@E; G = c3*E + c4*E2 (bf16).
// stg1: W = I + c1*E + c2*E2 + E2@G -> Wb (bf16); tacc += mean^T W (atomics).
__global__ __launch_bounds__(256) void k_poly(char* __restrict__ wsb, int stg) {
  __shared__ __attribute__((aligned(16))) u16 As[2][64 * 64];
  __shared__ __attribute__((aligned(16))) u16 Bs[2][64 * 64];
  const int tile = blockIdx.x;
  const int tr = tile >> 3, tc = tile & 7;
  const int r0 = tr * 64, c0 = tc * 64;
  const u16* Eb  = (const u16*)(wsb + WS_EB);
  const u16* E2b = (const u16*)(wsb + WS_E2B);
  const u16* Gb  = (const u16*)(wsb + WS_GB);
  const u16* Ab; const u16* Bb;
  if (stg == 0) { Ab = Eb;  Bb = Eb; }
  else          { Ab = E2b; Bb = Gb; }
  const int t = threadIdx.x;
  const int l = t & 63, w = t >> 6, wr = w >> 1, wc = w & 1;
  f32x4 acc[2][2] = {};
  stage64(As[0], Ab + (size_t)r0 * F, F, t);
  stage64(Bs[0], Bb + (size_t)c0 * F, F, t);
  __syncthreads();
  for (int it = 0; it < 8; ++it) {
    int cur = it & 1;
    if (it < 7) {
      stage64(As[cur ^ 1], Ab + (size_t)r0 * F + (it + 1) * 64, F, t);
      stage64(Bs[cur ^ 1], Bb + (size_t)c0 * F + (it + 1) * 64, F, t);
    }
    mm64(As[cur], Bs[cur], wr, wc, l, acc);
    __syncthreads();
  }
  const float* Ef  = (const float*)(wsb + WS_E);
  const float* E2f = (const float*)(wsb + WS_E2);
  const float* mean = (const float*)(wsb + WS_MEAN);
  float* tacc = (float*)(wsb + WS_TACC);
  const float c1 = -0.5f, c2 = 0.375f, c3 = -0.3125f, c4 = 35.0f / 128.0f;
#pragma unroll
  for (int n = 0; n < 2; ++n) {
    int cg = c0 + wc * 32 + n * 16 + (l & 15);
    float ts = 0.0f;
#pragma unroll
    for (int m = 0; m < 2; ++m) {
#pragma unroll
      for (int r = 0; r < 4; ++r) {
        int rg = r0 + wr * 32 + m * 16 + ((l >> 4) << 2) + r;
        size_t o = (size_t)rg * F + cg;
        float v = acc[m][n][r];
        if (stg == 0) {
          ((float*)(wsb + WS_E2))[o] = v;
          ((u16*)(wsb + WS_E2B))[o] = f2bf(v);
          ((u16*)(wsb + WS_GB))[o]  = f2bf(c3 * Ef[o] + c4 * v);
        } else {
          float wv = c1 * Ef[o] + c2 * E2f[o] + v + ((rg == cg) ? 1.0f : 0.0f);
          ((u16*)(wsb + WS_WB))[o] = f2bf(wv);
          ts += mean[rg] * wv;
        }
      }
    }
    if (stg == 1) atomicAdd(tacc + cg, ts);
  }
}

// ---------------- K6a: out = (xb@W - tacc)*w + b  (big-ws: pure bf16 GEMM) --------
__global__ __launch_bounds__(512) void k_out_b(const u16* __restrict__ xb,
                                               const u16* __restrict__ Wb,
                                               const float* __restrict__ tacc,
                                               const float* __restrict__ wgt,
                                               const float* __restrict__ bias,
                                               float* __restrict__ out) {
  __shared__ __attribute__((aligned(16))) u16 As[2][128 * 64];
  __shared__ __attribute__((aligned(16))) u16 Bs[2][128 * 64];
  const int b = blockIdx.x;
  const int i = b >> 3;
  const int rt = (b & 7) * 64 + (i >> 2), ct = i & 3;
  const int i0 = rt * 128, j0 = ct * 128;
  const int t = threadIdx.x;
  const int l = t & 63, w = t >> 6, wr = w >> 2, wc = w & 3;
  f32x4 acc[4][2] = {};
  const u16* Abase = xb + (size_t)i0 * F;
  const u16* Bbase = Wb + (size_t)j0 * F;
  stage512(As[0], Abase, F, t);
  stage512(Bs[0], Bbase, F, t);
  __syncthreads();
  for (int it = 0; it < 8; ++it) {
    int cur = it & 1;
    if (it < 7) {
      stage512(As[cur ^ 1], Abase + (it + 1) * 64, F, t);
      stage512(Bs[cur ^ 1], Bbase + (it + 1) * 64, F, t);
    }
    mm_step8(As[cur], Bs[cur], wr, wc, l, acc);
    __syncthreads();
  }
#pragma unroll
  for (int n = 0; n < 2; ++n) {
    int cg = j0 + wc * 32 + n * 16 + (l & 15);
    float mv = tacc[cg];
    float wv = wgt[cg], bv = bias[cg];
#pragma unroll
    for (int m = 0; m < 4; ++m) {
      int rb = i0 + wr * 64 + m * 16 + ((l >> 4) << 2);
#pragma unroll
      for (int r = 0; r < 4; ++r) {
        size_t o = (size_t)(rb + r) * F + cg;
        out[o] = (acc[m][n][r] - mv) * wv + bv;
      }
    }
  }
}

// ---------------- K6b: small-ws fallback (fp32 x reg-staged A) ----------------
__global__ __launch_bounds__(512) void k_out_f(const float* __restrict__ x,
                                               const u16* __restrict__ Wb,
                                               const float* __restrict__ tacc,
                                               const float* __restrict__ wgt,
                                               const float* __restrict__ bias,
                                               float* __restrict__ out) {
  __shared__ __attribute__((aligned(16))) u16 As[2][128 * 64];
  __shared__ __attribute__((aligned(16))) u16 Bs[2][128 * 64];
  const int b = blockIdx.x;
  const int i = b >> 3;
  const int rt = (b & 7) * 64 + (i >> 2), ct = i & 3;
  const int i0 = rt * 128, j0 = ct * 128;
  const int t = threadIdx.x;
  const int l = t & 63, w = t >> 6, wr = w >> 2, wc = w & 3;
  f32x4 acc[4][2] = {};
  float4 ld[4];
  stage512(Bs[0], Wb + (size_t)j0 * F, F, t);
#pragma unroll
  for (int q = 0; q < 4; ++q) {
    int idx = q * 512 + t, r = idx >> 4, kc = idx & 15;
    ld[q] = *(const float4*)(x + (size_t)(i0 + r) * F + kc * 4);
  }
#pragma unroll
  for (int q = 0; q < 4; ++q) {
    int idx = q * 512 + t, r = idx >> 4, kc = idx & 15;
    ushort4 o;
    o.x = f2bf(ld[q].x); o.y = f2bf(ld[q].y); o.z = f2bf(ld[q].z); o.w = f2bf(ld[q].w);
    *(ushort4*)(As[0] + r * 64 + (((kc >> 1) ^ (r & 7)) << 3) + ((kc & 1) << 2)) = o;
  }
  __syncthreads();
  for (int it = 0; it < 8; ++it) {
    int cur = it & 1;
    if (it < 7) {
      int kk = (it + 1) * 64;
#pragma unroll
      for (int q = 0; q < 4; ++q) {
        int idx = q * 512 + t, r = idx >> 4, kc = idx & 15;
        ld[q] = *(const float4*)(x + (size_t)(i0 + r) * F + kk + kc * 4);
      }
      stage512(Bs[cur ^ 1], Wb + (size_t)j0 * F + kk, F, t);
    }
    mm_step8(As[cur], Bs[cur], wr, wc, l, acc);
    if (it < 7) {
#pragma unroll
      for (int q = 0; q < 4; ++q) {
        int idx = q * 512 + t, r = idx >> 4, kc = idx & 15;
        ushort4 o;
        o.x = f2bf(ld[q].x); o.y = f2bf(ld[q].y); o.z = f2bf(ld[q].z); o.w = f2bf(ld[q].w);
        *(ushort4*)(As[cur ^ 1] + r * 64 + (((kc >> 1) ^ (r & 7)) << 3) + ((kc & 1) << 2)) = o;
      }
    }
    __syncthreads();
  }
#pragma unroll
  for (int n = 0; n < 2; ++n) {
    int cg = j0 + wc * 32 + n * 16 + (l & 15);
    float mv = tacc[cg];
    float wv = wgt[cg], bv = bias[cg];
#pragma unroll
    for (int m = 0; m < 4; ++m) {
      int rb = i0 + wr * 64 + m * 16 + ((l >> 4) << 2);
#pragma unroll
      for (int r = 0; r < 4; ++r) {
        size_t o = (size_t)(rb + r) * F + cg;
        out[o] = (acc[m][n][r] - mv) * wv + bv;
      }
    }
  }
}

extern "C" void kernel_launch(void* const* d_in, const int* in_sizes, int n_in,
                              void* d_out, int out_size, void* d_ws, size_t ws_size,
                              hipStream_t stream) {
  (void)in_sizes; (void)n_in; (void)out_size;
  const float* x      = (const float*)d_in[0];
  const float* weight = (const float*)d_in[1];
  const float* bias   = (const float*)d_in[2];
  float* out = (float*)d_out;
  char* ws   = (char*)d_ws;
  // xbT (64 MiB) overlays d_out; dead before k_out overwrites d_out.
  u16* xbT = (u16*)d_out;
  const bool big = ws_size >= (size_t)WS_NEED_BIG;
  u16* xb = big ? (u16*)(ws + WS_XB) : nullptr;

  float* S      = (float*)(ws + WS_S);
  float* colsum = (float*)(ws + WS_COLSUM);
  float* tacc   = (float*)(ws + WS_TACC);
  float* mean   = (float*)(ws + WS_MEAN);

  hipMemsetAsync(ws, 0, WS_MEAN, stream);  // zero S + colsum + tacc

  k_prep<<<dim3(512, 8), dim3(256), 0, stream>>>(x, xbT, colsum, xb);
  k_cov<<<dim3(320), dim3(256), 0, stream>>>(xbT, S);
  k_finalize<<<dim3(1024), dim3(256), 0, stream>>>(S, colsum, mean,
                                                   (float*)(ws + WS_E),
                                                   (u16*)(ws + WS_EB));
  k_poly<<<dim3(64), dim3(256), 0, stream>>>(ws, 0);
  k_poly<<<dim3(64), dim3(256), 0, stream>>>(ws, 1);
  if (big) {
    k_out_b<<<dim3(2048), dim3(512), 0, stream>>>(xb, (u16*)(ws + WS_WB),
                                                  tacc, weight, bias, out);
  } else {
    k_out_f<<<dim3(2048), dim3(512), 0, stream>>>(x, (u16*)(ws + WS_WB),
                                                  tacc, weight, bias, out);
  }
}